// Round 3
// baseline (184.840 us; speedup 1.0000x reference)
//
#include <hip/hip_runtime.h>

#define D 128

// ---------------- Kernel 1: h = relu(x @ W^T + b) * (mask_u >= 0.5) * 2 ----
// Full W transposed in LDS (64KB). 64-node tiles, 1 block per tile.
// Thread (nl,m): 4 consecutive nodes x 8 outs (cols 4m..4m+3 and 64+4m..+3).
// x read straight from global (16 lanes/wave share each address -> merged).
__global__ __launch_bounds__(256) void gemm_relu_drop_kernel(
    const float* __restrict__ x, const float* __restrict__ W,
    const float* __restrict__ bias, const float* __restrict__ mask_u,
    float* __restrict__ h, int n_nodes)
{
    __shared__ float Wt[D][D];   // Wt[d][o] = W[o][d]; 65536 B
    const int t = threadIdx.x;

    // Stage W transposed. item i: d = i>>5, col-group og = (i&31)*4.
    // LDS write addrs spread 4og -> 4-way (one-time). Global reads hit L2 after
    // the first blocks touch W.
    for (int i = t; i < D * 32; i += 256) {
        int d  = i >> 5;
        int og = (i & 31) << 2;
        float4 v;
        v.x = W[(size_t)(og + 0) * D + d];
        v.y = W[(size_t)(og + 1) * D + d];
        v.z = W[(size_t)(og + 2) * D + d];
        v.w = W[(size_t)(og + 3) * D + d];
        *(float4*)&Wt[d][og] = v;
    }
    __syncthreads();

    const int nl = t >> 4;          // 0..15 -> node group
    const int m  = t & 15;          // 0..15 -> col group
    const int c0 = 4 * m;
    const int c1 = 64 + 4 * m;
    const float4 b0 = *(const float4*)&bias[c0];
    const float4 b1 = *(const float4*)&bias[c1];

    const int n0 = blockIdx.x * 64 + 4 * nl;
    int nn[4];
    #pragma unroll
    for (int k = 0; k < 4; ++k) {
        int g = n0 + k;
        nn[k] = (g < n_nodes) ? g : (n_nodes - 1);   // clamped for safe loads
    }
    const float* xr[4];
    #pragma unroll
    for (int k = 0; k < 4; ++k) xr[k] = x + (size_t)nn[k] * D;

    float acc[4][8];
    #pragma unroll
    for (int k = 0; k < 4; ++k)
        #pragma unroll
        for (int j = 0; j < 8; ++j) acc[k][j] = 0.f;

    #pragma unroll 4
    for (int d4 = 0; d4 < D; d4 += 4) {
        float4 xv[4];
        #pragma unroll
        for (int k = 0; k < 4; ++k) xv[k] = *(const float4*)&xr[k][d4];
        #pragma unroll
        for (int dd = 0; dd < 4; ++dd) {
            float4 w0 = *(const float4*)&Wt[d4 + dd][c0];
            float4 w1 = *(const float4*)&Wt[d4 + dd][c1];
            #pragma unroll
            for (int k = 0; k < 4; ++k) {
                float xs = ((const float*)&xv[k])[dd];
                acc[k][0] = fmaf(xs, w0.x, acc[k][0]);
                acc[k][1] = fmaf(xs, w0.y, acc[k][1]);
                acc[k][2] = fmaf(xs, w0.z, acc[k][2]);
                acc[k][3] = fmaf(xs, w0.w, acc[k][3]);
                acc[k][4] = fmaf(xs, w1.x, acc[k][4]);
                acc[k][5] = fmaf(xs, w1.y, acc[k][5]);
                acc[k][6] = fmaf(xs, w1.z, acc[k][6]);
                acc[k][7] = fmaf(xs, w1.w, acc[k][7]);
            }
        }
    }

    #pragma unroll
    for (int k = 0; k < 4; ++k) {
        int g = n0 + k;
        if (g < n_nodes) {
            const size_t off = (size_t)g * D;
            float4 mk0 = *(const float4*)&mask_u[off + c0];
            float4 mk1 = *(const float4*)&mask_u[off + c1];
            float4 r0, r1;
            r0.x = fmaxf(acc[k][0] + b0.x, 0.f) * (mk0.x >= 0.5f ? 2.f : 0.f);
            r0.y = fmaxf(acc[k][1] + b0.y, 0.f) * (mk0.y >= 0.5f ? 2.f : 0.f);
            r0.z = fmaxf(acc[k][2] + b0.z, 0.f) * (mk0.z >= 0.5f ? 2.f : 0.f);
            r0.w = fmaxf(acc[k][3] + b0.w, 0.f) * (mk0.w >= 0.5f ? 2.f : 0.f);
            r1.x = fmaxf(acc[k][4] + b1.x, 0.f) * (mk1.x >= 0.5f ? 2.f : 0.f);
            r1.y = fmaxf(acc[k][5] + b1.y, 0.f) * (mk1.y >= 0.5f ? 2.f : 0.f);
            r1.z = fmaxf(acc[k][6] + b1.z, 0.f) * (mk1.z >= 0.5f ? 2.f : 0.f);
            r1.w = fmaxf(acc[k][7] + b1.w, 0.f) * (mk1.w >= 0.5f ? 2.f : 0.f);
            *(float4*)&h[off + c0] = r0;
            *(float4*)&h[off + c1] = r1;
        }
    }
}

// ---------------- CSR build: histogram -> exclusive scan -> bucket scatter --
__global__ __launch_bounds__(256) void hist_kernel(
    const int* __restrict__ dst, int* __restrict__ cnt, int n_edges)
{
    int i = blockIdx.x * 256 + threadIdx.x;
    if (i < n_edges) atomicAdd(&cnt[dst[i]], 1);
}

__global__ __launch_bounds__(256) void scan_partial_kernel(
    const int* __restrict__ cnt, int* __restrict__ bsum, int n)
{
    __shared__ int s[256];
    int t = threadIdx.x;
    int i = blockIdx.x * 256 + t;
    s[t] = (i < n) ? cnt[i] : 0;
    __syncthreads();
    for (int o = 128; o > 0; o >>= 1) {
        if (t < o) s[t] += s[t + o];
        __syncthreads();
    }
    if (t == 0) bsum[blockIdx.x] = s[0];
}

__global__ __launch_bounds__(256) void scan_bsum_kernel(int* __restrict__ bsum, int nb)
{
    __shared__ int s[256];
    int t = threadIdx.x;
    int v = (t < nb) ? bsum[t] : 0;
    s[t] = v;
    __syncthreads();
    for (int o = 1; o < 256; o <<= 1) {
        int add = (t >= o) ? s[t - o] : 0;
        __syncthreads();
        s[t] += add;
        __syncthreads();
    }
    if (t < nb) bsum[t] = s[t] - v;   // exclusive
}

__global__ __launch_bounds__(256) void scan_final_kernel(
    int* __restrict__ offs, const int* __restrict__ bsum, int n)
{
    __shared__ int s[256];
    int t = threadIdx.x;
    int i = blockIdx.x * 256 + t;
    int v = (i < n) ? offs[i] : 0;
    s[t] = v;
    __syncthreads();
    for (int o = 1; o < 256; o <<= 1) {
        int add = (t >= o) ? s[t - o] : 0;
        __syncthreads();
        s[t] += add;
        __syncthreads();
    }
    if (i < n) offs[i] = s[t] - v + bsum[blockIdx.x];
}

__global__ __launch_bounds__(256) void scatter_build_kernel(
    const int* __restrict__ src, const int* __restrict__ dst,
    int* __restrict__ offs, int* __restrict__ srcs, int n_edges)
{
    int i = blockIdx.x * 256 + threadIdx.x;
    if (i < n_edges) {
        int pos = atomicAdd(&offs[dst[i]], 1);
        srcs[pos] = src[i];
    }
}

// ---------------- Gather-reduce: out[n] = sum_{e: dst=n} h[src_e] ----------
__global__ __launch_bounds__(256) void gather_reduce_kernel(
    const float* __restrict__ h, const int* __restrict__ srcs,
    const int* __restrict__ offs, float* __restrict__ out, int n_nodes)
{
    const int t = threadIdx.x;
    const int node = blockIdx.x * 8 + (t >> 5);
    if (node >= n_nodes) return;
    const int c = (t & 31) * 4;
    const int start = (node == 0) ? 0 : offs[node - 1];
    const int end   = offs[node];
    float4 acc = make_float4(0.f, 0.f, 0.f, 0.f);
    int i = start;
    for (; i + 1 < end; i += 2) {   // 2-edge unroll for load-latency ILP
        int s0 = srcs[i], s1 = srcs[i + 1];
        float4 v0 = *(const float4*)&h[(size_t)s0 * D + c];
        float4 v1 = *(const float4*)&h[(size_t)s1 * D + c];
        acc.x += v0.x + v1.x; acc.y += v0.y + v1.y;
        acc.z += v0.z + v1.z; acc.w += v0.w + v1.w;
    }
    if (i < end) {
        int s0 = srcs[i];
        float4 v0 = *(const float4*)&h[(size_t)s0 * D + c];
        acc.x += v0.x; acc.y += v0.y; acc.z += v0.z; acc.w += v0.w;
    }
    *(float4*)&out[(size_t)node * D + c] = acc;
}

// ---------------- Fallback: direct atomic scatter ---------------------------
__global__ __launch_bounds__(256) void scatter_atomic_kernel(
    const float* __restrict__ h, const int* __restrict__ src,
    const int* __restrict__ dst, float* __restrict__ out, int n_edges)
{
    const int t = threadIdx.x;
    const int e = blockIdx.x * 8 + (t >> 5);
    if (e >= n_edges) return;
    const int c = (t & 31) * 4;
    const int s  = src[e];
    const int dd = dst[e];
    float4 v = *(const float4*)&h[(size_t)s * D + c];
    float* o = &out[(size_t)dd * D + c];
    atomicAdd(o + 0, v.x);
    atomicAdd(o + 1, v.y);
    atomicAdd(o + 2, v.z);
    atomicAdd(o + 3, v.w);
}

extern "C" void kernel_launch(void* const* d_in, const int* in_sizes, int n_in,
                              void* d_out, int out_size, void* d_ws, size_t ws_size,
                              hipStream_t stream) {
    const float* x      = (const float*)d_in[0];
    const float* W      = (const float*)d_in[1];
    const float* bias   = (const float*)d_in[2];
    const float* mask_u = (const float*)d_in[3];
    const int*   src    = (const int*)d_in[4];
    const int*   dst    = (const int*)d_in[5];
    float* out = (float*)d_out;

    const int n_nodes = in_sizes[0] / D;
    const int n_edges = in_sizes[4];

    // ws layout
    const size_t h_bytes = (size_t)n_nodes * D * sizeof(float);
    float* h    = (float*)d_ws;
    int*   offs = (int*)((char*)d_ws + h_bytes);              // n_nodes ints
    int*   bsum = offs + n_nodes;                             // 256 ints
    int*   srcs = bsum + 256;                                 // n_edges ints
    const size_t needed = h_bytes + ((size_t)n_nodes + 256 + n_edges) * sizeof(int);

    const int n_tiles = (n_nodes + 63) / 64;
    gemm_relu_drop_kernel<<<n_tiles, 256, 0, stream>>>(x, W, bias, mask_u, h, n_nodes);

    const int eb  = (n_edges + 255) / 256;
    const int nbk = (n_nodes + 255) / 256;

    if (ws_size >= needed && nbk <= 256) {
        hipMemsetAsync(offs, 0, (size_t)n_nodes * sizeof(int), stream);
        hist_kernel<<<eb, 256, 0, stream>>>(dst, offs, n_edges);
        scan_partial_kernel<<<nbk, 256, 0, stream>>>(offs, bsum, n_nodes);
        scan_bsum_kernel<<<1, 256, 0, stream>>>(bsum, nbk);
        scan_final_kernel<<<nbk, 256, 0, stream>>>(offs, bsum, n_nodes);
        scatter_build_kernel<<<eb, 256, 0, stream>>>(src, dst, offs, srcs, n_edges);
        gather_reduce_kernel<<<(n_nodes + 7) / 8, 256, 0, stream>>>(
            h, srcs, offs, out, n_nodes);
    } else {
        hipMemsetAsync(d_out, 0, (size_t)out_size * sizeof(float), stream);
        scatter_atomic_kernel<<<(n_edges + 7) / 8, 256, 0, stream>>>(
            h, src, dst, out, n_edges);
    }
}

// Round 4
// 132.958 us; speedup vs baseline: 1.3902x; 1.3902x over previous
//
#include <hip/hip_runtime.h>

#define D 128
#define TILE_N 64
#define BPITCH 136   // bf16 elems per LDS row (128 + 8 pad -> spreads bank groups)

typedef __attribute__((ext_vector_type(8))) short  short8;
typedef __attribute__((ext_vector_type(4))) float  f32x4;
typedef __attribute__((ext_vector_type(4))) unsigned short ushortx4;

__device__ inline unsigned short f32_to_bf16(float f) {
    unsigned int u = __float_as_uint(f);
    unsigned int r = (u + 0x7FFFu + ((u >> 16) & 1u)) >> 16;   // RNE
    return (unsigned short)r;
}
__device__ inline float bf16_to_f32(unsigned short s) {
    return __uint_as_float(((unsigned int)s) << 16);
}

// ---- Kernel 1: h(bf16) = relu(x @ W^T + b) * (mask_u >= 0.5) * 2 ----------
// MFMA 16x16x32 bf16. B-operand = W rows directly (out = x*W^T => B[k][o]=W[o][k]).
// Persistent blocks + dynamic tile counter; hist fused at the end.
__global__ __launch_bounds__(256) void gemm_mfma_kernel(
    const float* __restrict__ x, const float* __restrict__ W,
    const float* __restrict__ bias, const float* __restrict__ mask_u,
    unsigned short* __restrict__ h, int n_nodes, int n_tiles,
    int* __restrict__ tile_counter,
    const int* __restrict__ dst, int* __restrict__ cnt, int n_edges)
{
    __shared__ unsigned short Bt[D * BPITCH];       // W as bf16, row o, 34816 B
    __shared__ unsigned short At[TILE_N * BPITCH];  // x tile as bf16, 17408 B
    __shared__ int s_tile;
    const int t = threadIdx.x;

    // Stage W once per block: coalesced f32 reads, contiguous bf16 LDS writes.
    for (int idx = t; idx < D * 32; idx += 256) {
        int row = idx >> 5;
        int seg = idx & 31;
        float4 v = *(const float4*)&W[(size_t)row * D + seg * 4];
        ushortx4 u;
        u[0] = f32_to_bf16(v.x); u[1] = f32_to_bf16(v.y);
        u[2] = f32_to_bf16(v.z); u[3] = f32_to_bf16(v.w);
        *(ushortx4*)&Bt[row * BPITCH + seg * 4] = u;
    }

    const int lane = t & 63;
    const int w    = t >> 6;        // wave id 0..3 -> 16-node strip
    const int fr   = lane & 15;     // fragment row/col index
    const int fg   = lane >> 4;     // 0..3

    // bias per output column (8 col-tiles), hoisted
    float bs[8];
    #pragma unroll
    for (int c = 0; c < 8; ++c) bs[c] = bias[16 * c + fr];

    for (;;) {
        __syncthreads();            // protect At reuse + s_tile
        if (t == 0) s_tile = atomicAdd(tile_counter, 1);
        __syncthreads();
        const int tile = s_tile;
        if (tile >= n_tiles) break;

        // Stage A tile: 64 nodes x 128 d, f32 -> bf16
        const int n0 = tile * TILE_N;
        for (int idx = t; idx < TILE_N * 32; idx += 256) {
            int row = idx >> 5;
            int seg = idx & 31;
            int gn  = n0 + row;
            float4 v = (gn < n_nodes) ? *(const float4*)&x[(size_t)gn * D + seg * 4]
                                      : make_float4(0.f, 0.f, 0.f, 0.f);
            ushortx4 u;
            u[0] = f32_to_bf16(v.x); u[1] = f32_to_bf16(v.y);
            u[2] = f32_to_bf16(v.z); u[3] = f32_to_bf16(v.w);
            *(ushortx4*)&At[row * BPITCH + seg * 4] = u;
        }
        __syncthreads();

        f32x4 acc[8];
        #pragma unroll
        for (int c = 0; c < 8; ++c) acc[c] = (f32x4){0.f, 0.f, 0.f, 0.f};

        #pragma unroll
        for (int s = 0; s < 4; ++s) {   // K = 128 in 4 steps of 32
            short8 a = *(const short8*)&At[(16 * w + fr) * BPITCH + s * 32 + fg * 8];
            #pragma unroll
            for (int c = 0; c < 8; ++c) {
                short8 b = *(const short8*)&Bt[(16 * c + fr) * BPITCH + s * 32 + fg * 8];
                acc[c] = __builtin_amdgcn_mfma_f32_16x16x32_bf16(a, b, acc[c], 0, 0, 0);
            }
        }

        // Epilogue: D[row=(fg*4+r)][col=16c+fr]; bias+relu+dropout, store bf16
        const int n_base = n0 + 16 * w;
        #pragma unroll
        for (int c = 0; c < 8; ++c) {
            const int col = 16 * c + fr;
            #pragma unroll
            for (int r = 0; r < 4; ++r) {
                const int node = n_base + fg * 4 + r;
                if (node < n_nodes) {
                    float v = acc[c][r] + bs[c];
                    v = fmaxf(v, 0.f);
                    float mk = mask_u[(size_t)node * D + col];
                    v *= (mk >= 0.5f) ? 2.f : 0.f;
                    h[(size_t)node * D + col] = f32_to_bf16(v);
                }
            }
        }
    }

    // Fused histogram (cnt pre-zeroed by memset before this kernel)
    const int stride = gridDim.x * 256;
    for (int i = blockIdx.x * 256 + t; i < n_edges; i += stride)
        atomicAdd(&cnt[dst[i]], 1);
}

// ---------------- CSR build: scan + bucket scatter (proven in round 2) -----
__global__ __launch_bounds__(256) void scan_partial_kernel(
    const int* __restrict__ cnt, int* __restrict__ bsum, int n)
{
    __shared__ int s[256];
    int t = threadIdx.x;
    int i = blockIdx.x * 256 + t;
    s[t] = (i < n) ? cnt[i] : 0;
    __syncthreads();
    for (int o = 128; o > 0; o >>= 1) {
        if (t < o) s[t] += s[t + o];
        __syncthreads();
    }
    if (t == 0) bsum[blockIdx.x] = s[0];
}

__global__ __launch_bounds__(256) void scan_bsum_kernel(int* __restrict__ bsum, int nb)
{
    __shared__ int s[256];
    int t = threadIdx.x;
    int v = (t < nb) ? bsum[t] : 0;
    s[t] = v;
    __syncthreads();
    for (int o = 1; o < 256; o <<= 1) {
        int add = (t >= o) ? s[t - o] : 0;
        __syncthreads();
        s[t] += add;
        __syncthreads();
    }
    if (t < nb) bsum[t] = s[t] - v;   // exclusive
}

__global__ __launch_bounds__(256) void scan_final_kernel(
    int* __restrict__ offs, const int* __restrict__ bsum, int n)
{
    __shared__ int s[256];
    int t = threadIdx.x;
    int i = blockIdx.x * 256 + t;
    int v = (i < n) ? offs[i] : 0;
    s[t] = v;
    __syncthreads();
    for (int o = 1; o < 256; o <<= 1) {
        int add = (t >= o) ? s[t - o] : 0;
        __syncthreads();
        s[t] += add;
        __syncthreads();
    }
    if (i < n) offs[i] = s[t] - v + bsum[blockIdx.x];
}

__global__ __launch_bounds__(256) void scatter_build_kernel(
    const int* __restrict__ src, const int* __restrict__ dst,
    int* __restrict__ offs, int* __restrict__ srcs, int n_edges)
{
    int i = blockIdx.x * 256 + threadIdx.x;
    if (i < n_edges) {
        int pos = atomicAdd(&offs[dst[i]], 1);
        srcs[pos] = src[i];
    }
}

// ---- Gather-reduce (bf16 h): out[n] = sum_{e: dst=n} h[src_e] -------------
// 16 lanes per node, 8 bf16 cols/lane via b128 loads.
__global__ __launch_bounds__(256) void gather_reduce_kernel(
    const unsigned short* __restrict__ h, const int* __restrict__ srcs,
    const int* __restrict__ offs, float* __restrict__ out, int n_nodes)
{
    const int t = threadIdx.x;
    const int node = blockIdx.x * 16 + (t >> 4);
    if (node >= n_nodes) return;
    const int cb = (t & 15) * 8;
    const int start = (node == 0) ? 0 : offs[node - 1];
    const int end   = offs[node];
    float acc[8];
    #pragma unroll
    for (int j = 0; j < 8; ++j) acc[j] = 0.f;

    int i = start;
    for (; i + 1 < end; i += 2) {
        int s0 = srcs[i], s1 = srcs[i + 1];
        short8 v0 = *(const short8*)&h[(size_t)s0 * D + cb];
        short8 v1 = *(const short8*)&h[(size_t)s1 * D + cb];
        #pragma unroll
        for (int j = 0; j < 8; ++j)
            acc[j] += bf16_to_f32((unsigned short)v0[j]) +
                      bf16_to_f32((unsigned short)v1[j]);
    }
    if (i < end) {
        int s0 = srcs[i];
        short8 v0 = *(const short8*)&h[(size_t)s0 * D + cb];
        #pragma unroll
        for (int j = 0; j < 8; ++j) acc[j] += bf16_to_f32((unsigned short)v0[j]);
    }

    float4 o0 = make_float4(acc[0], acc[1], acc[2], acc[3]);
    float4 o1 = make_float4(acc[4], acc[5], acc[6], acc[7]);
    *(float4*)&out[(size_t)node * D + cb]     = o0;
    *(float4*)&out[(size_t)node * D + cb + 4] = o1;
}

// ---------------- Fallback: direct atomic scatter (bf16 h) -----------------
__global__ __launch_bounds__(256) void scatter_atomic_kernel(
    const unsigned short* __restrict__ h, const int* __restrict__ src,
    const int* __restrict__ dst, float* __restrict__ out, int n_edges)
{
    const int t = threadIdx.x;
    const int e = blockIdx.x * 16 + (t >> 4);
    if (e >= n_edges) return;
    const int cb = (t & 15) * 8;
    const int s  = src[e];
    const int dd = dst[e];
    short8 v = *(const short8*)&h[(size_t)s * D + cb];
    float* o = &out[(size_t)dd * D + cb];
    #pragma unroll
    for (int j = 0; j < 8; ++j) atomicAdd(o + j, bf16_to_f32((unsigned short)v[j]));
}

extern "C" void kernel_launch(void* const* d_in, const int* in_sizes, int n_in,
                              void* d_out, int out_size, void* d_ws, size_t ws_size,
                              hipStream_t stream) {
    const float* x      = (const float*)d_in[0];
    const float* W      = (const float*)d_in[1];
    const float* bias   = (const float*)d_in[2];
    const float* mask_u = (const float*)d_in[3];
    const int*   src    = (const int*)d_in[4];
    const int*   dst    = (const int*)d_in[5];
    float* out = (float*)d_out;

    const int n_nodes = in_sizes[0] / D;
    const int n_edges = in_sizes[4];
    const int n_tiles = (n_nodes + TILE_N - 1) / TILE_N;

    // ws layout: [h bf16][offs int][bsum 256][counter 1][srcs int]
    const size_t h_bytes = (size_t)n_nodes * D * sizeof(unsigned short);
    unsigned short* h   = (unsigned short*)d_ws;
    int* offs    = (int*)((char*)d_ws + h_bytes);
    int* bsum    = offs + n_nodes;
    int* counter = bsum + 256;
    int* srcs    = counter + 1;
    const size_t needed = h_bytes + ((size_t)n_nodes + 257 + n_edges) * sizeof(int);

    const int eb  = (n_edges + 255) / 256;
    const int nbk = (n_nodes + 255) / 256;

    if (ws_size >= needed && nbk <= 256) {
        // zero offs (hist target) + counter in one memset
        hipMemsetAsync(offs, 0, ((size_t)n_nodes + 257) * sizeof(int), stream);
        gemm_mfma_kernel<<<768, 256, 0, stream>>>(
            x, W, bias, mask_u, h, n_nodes, n_tiles, counter, dst, offs, n_edges);
        scan_partial_kernel<<<nbk, 256, 0, stream>>>(offs, bsum, n_nodes);
        scan_bsum_kernel<<<1, 256, 0, stream>>>(bsum, nbk);
        scan_final_kernel<<<nbk, 256, 0, stream>>>(offs, bsum, n_nodes);
        scatter_build_kernel<<<eb, 256, 0, stream>>>(src, dst, offs, srcs, n_edges);
        gather_reduce_kernel<<<(n_nodes + 15) / 16, 256, 0, stream>>>(
            h, srcs, offs, out, n_nodes);
    } else {
        hipMemsetAsync(counter, 0, sizeof(int), stream);
        gemm_mfma_kernel<<<768, 256, 0, stream>>>(
            x, W, bias, mask_u, h, n_nodes, n_tiles, counter, dst, offs, 0);
        hipMemsetAsync(d_out, 0, (size_t)out_size * sizeof(float), stream);
        scatter_atomic_kernel<<<(n_edges + 15) / 16, 256, 0, stream>>>(
            h, src, dst, out, n_edges);
    }
}

// Round 5
// 128.366 us; speedup vs baseline: 1.4400x; 1.0358x over previous
//
#include <hip/hip_runtime.h>

#define D 128
#define TILE_N 64
#define HPITCH 132   // bf16 pitch for epilogue LDS tile -> conflict-free banks

typedef __attribute__((ext_vector_type(8))) short  short8;
typedef __attribute__((ext_vector_type(4))) float  f32x4;

__device__ inline unsigned short f32_to_bf16(float f) {
    unsigned int u = __float_as_uint(f);
    unsigned int r = (u + 0x7FFFu + ((u >> 16) & 1u)) >> 16;   // RNE
    return (unsigned short)r;
}
__device__ inline float bf16_to_f32(unsigned short s) {
    return __uint_as_float(((unsigned int)s) << 16);
}
__device__ inline short8 pack_bf16x8(float4 a, float4 b) {
    short8 u;
    u[0] = (short)f32_to_bf16(a.x); u[1] = (short)f32_to_bf16(a.y);
    u[2] = (short)f32_to_bf16(a.z); u[3] = (short)f32_to_bf16(a.w);
    u[4] = (short)f32_to_bf16(b.x); u[5] = (short)f32_to_bf16(b.y);
    u[6] = (short)f32_to_bf16(b.z); u[7] = (short)f32_to_bf16(b.w);
    return u;
}

// ---- prep: W (f32) -> Wb (bf16) once; fused dst-histogram ------------------
__global__ __launch_bounds__(256) void prep_kernel(
    const float* __restrict__ W, unsigned short* __restrict__ Wb,
    const int* __restrict__ dst, int* __restrict__ cnt, int n_edges)
{
    const int tid = blockIdx.x * 256 + threadIdx.x;
    if (tid < (D * D) / 8) {
        float4 v0 = *(const float4*)&W[tid * 8];
        float4 v1 = *(const float4*)&W[tid * 8 + 4];
        *(short8*)&Wb[tid * 8] = pack_bf16x8(v0, v1);
    }
    const int stride = gridDim.x * 256;
    for (int i = tid; i < n_edges; i += stride)
        atomicAdd(&cnt[dst[i]], 1);
}

// ---- GEMM: h(bf16) = relu(x @ W^T + b) * (mask_u >= 0.5) * 2 ---------------
// One 64-node tile per block. A: f32 from global + cvt (each row read once).
// B: short8 straight from L1/L2-resident Wb. LDS only for epilogue transpose.
__global__ __launch_bounds__(256, 4) void gemm_mfma_kernel(
    const float* __restrict__ x, const unsigned short* __restrict__ Wb,
    const float* __restrict__ bias, const float* __restrict__ mask_u,
    unsigned short* __restrict__ h, int n_nodes)
{
    __shared__ unsigned short ht[TILE_N * HPITCH];   // 16896 B
    const int t    = threadIdx.x;
    const int lane = t & 63;
    const int w    = t >> 6;      // wave -> 16-row strip of the tile
    const int fr   = lane & 15;
    const int fg   = lane >> 4;

    const int n0 = blockIdx.x * TILE_N;

    float bs[8];
    #pragma unroll
    for (int c = 0; c < 8; ++c) bs[c] = bias[16 * c + fr];

    int arow = n0 + 16 * w + fr;
    if (arow >= n_nodes) arow = n_nodes - 1;          // clamped (safe dup loads)
    const float* xrow = x + (size_t)arow * D;

    f32x4 acc[8];
    #pragma unroll
    for (int c = 0; c < 8; ++c) acc[c] = (f32x4){0.f, 0.f, 0.f, 0.f};

    #pragma unroll
    for (int s = 0; s < 4; ++s) {                     // K = 128, 4 x 32
        float4 a0 = *(const float4*)&xrow[s * 32 + fg * 8];
        float4 a1 = *(const float4*)&xrow[s * 32 + fg * 8 + 4];
        short8 a  = pack_bf16x8(a0, a1);
        #pragma unroll
        for (int c = 0; c < 8; ++c) {
            short8 b = *(const short8*)&Wb[(16 * c + fr) * D + s * 32 + fg * 8];
            acc[c] = __builtin_amdgcn_mfma_f32_16x16x32_bf16(a, b, acc[c], 0, 0, 0);
        }
    }

    // phase 1: bias + relu, scatter bf16 into LDS tile (conflict-free, pitch 132)
    #pragma unroll
    for (int c = 0; c < 8; ++c) {
        const int col = 16 * c + fr;
        #pragma unroll
        for (int r = 0; r < 4; ++r) {
            const int rl = 16 * w + fg * 4 + r;
            float v = fmaxf(acc[c][r] + bs[c], 0.f);
            ht[rl * HPITCH + col] = f32_to_bf16(v);
        }
    }
    __syncthreads();

    // phase 2: dropout + fully coalesced mask loads / h stores
    const int cg = t & 15;                            // 8-col group
    const int r0 = t >> 4;                            // 0..15
    #pragma unroll
    for (int rr = 0; rr < 4; ++rr) {
        const int row  = 16 * rr + r0;
        const int node = n0 + row;
        if (node < n_nodes) {
            short8 hv = *(const short8*)&ht[row * HPITCH + cg * 8];
            const size_t off = (size_t)node * D + cg * 8;
            float4 m0 = *(const float4*)&mask_u[off];
            float4 m1 = *(const float4*)&mask_u[off + 4];
            const float* mp = (const float*)&m0;
            short8 o;
            #pragma unroll
            for (int j = 0; j < 8; ++j) {
                float mk = (j < 4) ? ((const float*)&m0)[j] : ((const float*)&m1)[j - 4];
                float v  = bf16_to_f32((unsigned short)hv[j]) * 2.f;
                o[j] = (mk >= 0.5f) ? (short)f32_to_bf16(v) : (short)0;
            }
            (void)mp;
            *(short8*)&h[off] = o;
        }
    }
}

// ---------------- CSR build: scan + bucket scatter --------------------------
__global__ __launch_bounds__(256) void scan_partial_kernel(
    const int* __restrict__ cnt, int* __restrict__ bsum, int n)
{
    __shared__ int s[256];
    int t = threadIdx.x;
    int i = blockIdx.x * 256 + t;
    s[t] = (i < n) ? cnt[i] : 0;
    __syncthreads();
    for (int o = 128; o > 0; o >>= 1) {
        if (t < o) s[t] += s[t + o];
        __syncthreads();
    }
    if (t == 0) bsum[blockIdx.x] = s[0];
}

__global__ __launch_bounds__(256) void scan_bsum_kernel(int* __restrict__ bsum, int nb)
{
    __shared__ int s[256];
    int t = threadIdx.x;
    int v = (t < nb) ? bsum[t] : 0;
    s[t] = v;
    __syncthreads();
    for (int o = 1; o < 256; o <<= 1) {
        int add = (t >= o) ? s[t - o] : 0;
        __syncthreads();
        s[t] += add;
        __syncthreads();
    }
    if (t < nb) bsum[t] = s[t] - v;   // exclusive
}

__global__ __launch_bounds__(256) void scan_final_kernel(
    int* __restrict__ offs, const int* __restrict__ bsum, int n)
{
    __shared__ int s[256];
    int t = threadIdx.x;
    int i = blockIdx.x * 256 + t;
    int v = (i < n) ? offs[i] : 0;
    s[t] = v;
    __syncthreads();
    for (int o = 1; o < 256; o <<= 1) {
        int add = (t >= o) ? s[t - o] : 0;
        __syncthreads();
        s[t] += add;
        __syncthreads();
    }
    if (i < n) offs[i] = s[t] - v + bsum[blockIdx.x];
}

__global__ __launch_bounds__(256) void scatter_build_kernel(
    const int* __restrict__ src, const int* __restrict__ dst,
    int* __restrict__ offs, int* __restrict__ srcs, int n_edges)
{
    int i = blockIdx.x * 256 + threadIdx.x;
    if (i < n_edges) {
        int pos = atomicAdd(&offs[dst[i]], 1);
        srcs[pos] = src[i];
    }
}

// ---- Gather-reduce (bf16 h): out[n] = sum_{e: dst=n} h[src_e] --------------
__global__ __launch_bounds__(256) void gather_reduce_kernel(
    const unsigned short* __restrict__ h, const int* __restrict__ srcs,
    const int* __restrict__ offs, float* __restrict__ out, int n_nodes)
{
    const int t = threadIdx.x;
    const int node = blockIdx.x * 16 + (t >> 4);
    if (node >= n_nodes) return;
    const int cb = (t & 15) * 8;
    const int start = (node == 0) ? 0 : offs[node - 1];
    const int end   = offs[node];
    float acc[8];
    #pragma unroll
    for (int j = 0; j < 8; ++j) acc[j] = 0.f;

    int i = start;
    for (; i + 1 < end; i += 2) {
        int s0 = srcs[i], s1 = srcs[i + 1];
        short8 v0 = *(const short8*)&h[(size_t)s0 * D + cb];
        short8 v1 = *(const short8*)&h[(size_t)s1 * D + cb];
        #pragma unroll
        for (int j = 0; j < 8; ++j)
            acc[j] += bf16_to_f32((unsigned short)v0[j]) +
                      bf16_to_f32((unsigned short)v1[j]);
    }
    if (i < end) {
        int s0 = srcs[i];
        short8 v0 = *(const short8*)&h[(size_t)s0 * D + cb];
        #pragma unroll
        for (int j = 0; j < 8; ++j) acc[j] += bf16_to_f32((unsigned short)v0[j]);
    }

    *(float4*)&out[(size_t)node * D + cb]     = make_float4(acc[0], acc[1], acc[2], acc[3]);
    *(float4*)&out[(size_t)node * D + cb + 4] = make_float4(acc[4], acc[5], acc[6], acc[7]);
}

// ---------------- Fallback: direct atomic scatter (bf16 h) ------------------
__global__ __launch_bounds__(256) void scatter_atomic_kernel(
    const unsigned short* __restrict__ h, const int* __restrict__ src,
    const int* __restrict__ dst, float* __restrict__ out, int n_edges)
{
    const int t = threadIdx.x;
    const int e = blockIdx.x * 16 + (t >> 4);
    if (e >= n_edges) return;
    const int cb = (t & 15) * 8;
    const int s  = src[e];
    const int dd = dst[e];
    short8 v = *(const short8*)&h[(size_t)s * D + cb];
    float* o = &out[(size_t)dd * D + cb];
    #pragma unroll
    for (int j = 0; j < 8; ++j) atomicAdd(o + j, bf16_to_f32((unsigned short)v[j]));
}

extern "C" void kernel_launch(void* const* d_in, const int* in_sizes, int n_in,
                              void* d_out, int out_size, void* d_ws, size_t ws_size,
                              hipStream_t stream) {
    const float* x      = (const float*)d_in[0];
    const float* W      = (const float*)d_in[1];
    const float* bias   = (const float*)d_in[2];
    const float* mask_u = (const float*)d_in[3];
    const int*   src    = (const int*)d_in[4];
    const int*   dst    = (const int*)d_in[5];
    float* out = (float*)d_out;

    const int n_nodes = in_sizes[0] / D;
    const int n_edges = in_sizes[4];
    const int n_tiles = (n_nodes + TILE_N - 1) / TILE_N;

    // ws layout: [Wb bf16 64KB][h bf16][offs][bsum 256][srcs]
    unsigned short* Wb = (unsigned short*)d_ws;
    const size_t wb_bytes = (size_t)D * D * sizeof(unsigned short);
    unsigned short* h  = (unsigned short*)((char*)d_ws + wb_bytes);
    const size_t h_bytes = (size_t)n_nodes * D * sizeof(unsigned short);
    int* offs = (int*)((char*)d_ws + wb_bytes + h_bytes);
    int* bsum = offs + n_nodes;
    int* srcs = bsum + 256;
    const size_t needed = wb_bytes + h_bytes +
                          ((size_t)n_nodes + 256 + n_edges) * sizeof(int);

    const int eb  = (n_edges + 255) / 256;
    const int nbk = (n_nodes + 255) / 256;
    const int pb  = (eb > 8) ? eb : 8;     // prep grid covers W conv + hist

    if (ws_size >= needed && nbk <= 256) {
        hipMemsetAsync(offs, 0, (size_t)n_nodes * sizeof(int), stream);
        prep_kernel<<<pb, 256, 0, stream>>>(W, Wb, dst, offs, n_edges);
        gemm_mfma_kernel<<<n_tiles, 256, 0, stream>>>(
            x, Wb, bias, mask_u, h, n_nodes);
        scan_partial_kernel<<<nbk, 256, 0, stream>>>(offs, bsum, n_nodes);
        scan_bsum_kernel<<<1, 256, 0, stream>>>(bsum, nbk);
        scan_final_kernel<<<nbk, 256, 0, stream>>>(offs, bsum, n_nodes);
        scatter_build_kernel<<<eb, 256, 0, stream>>>(src, dst, offs, srcs, n_edges);
        gather_reduce_kernel<<<(n_nodes + 15) / 16, 256, 0, stream>>>(
            h, srcs, offs, out, n_nodes);
    } else {
        prep_kernel<<<8, 256, 0, stream>>>(W, Wb, dst, nullptr, 0);
        gemm_mfma_kernel<<<n_tiles, 256, 0, stream>>>(
            x, Wb, bias, mask_u, h, n_nodes);
        hipMemsetAsync(d_out, 0, (size_t)out_size * sizeof(float), stream);
        scatter_atomic_kernel<<<(n_edges + 15) / 16, 256, 0, stream>>>(
            h, src, dst, out, n_edges);
    }
}

// Round 7
// 124.030 us; speedup vs baseline: 1.4903x; 1.0350x over previous
//
#include <hip/hip_runtime.h>

#define D 128
#define TILE_N 64
#define HPITCH 132   // bf16 pitch for epilogue LDS tile -> conflict-free banks

typedef __attribute__((ext_vector_type(8))) short  short8;
typedef __attribute__((ext_vector_type(4))) float  f32x4;

__device__ inline unsigned short f32_to_bf16(float f) {
    unsigned int u = __float_as_uint(f);
    unsigned int r = (u + 0x7FFFu + ((u >> 16) & 1u)) >> 16;   // RNE
    return (unsigned short)r;
}
__device__ inline float bf16_to_f32(unsigned short s) {
    return __uint_as_float(((unsigned int)s) << 16);
}
__device__ inline short8 pack_bf16x8(float4 a, float4 b) {
    short8 u;
    u[0] = (short)f32_to_bf16(a.x); u[1] = (short)f32_to_bf16(a.y);
    u[2] = (short)f32_to_bf16(a.z); u[3] = (short)f32_to_bf16(a.w);
    u[4] = (short)f32_to_bf16(b.x); u[5] = (short)f32_to_bf16(b.y);
    u[6] = (short)f32_to_bf16(b.z); u[7] = (short)f32_to_bf16(b.w);
    return u;
}

// ---- zero: custom buffer zeroing (rocclr fill was 40us for 200KB!) --------
__global__ __launch_bounds__(256) void zero_kernel(int* __restrict__ p, int n)
{
    int i = blockIdx.x * 256 + threadIdx.x;
    if (i < n) p[i] = 0;
}

// ---- prep: W (f32) -> Wb (bf16) once; fused dst-histogram ------------------
__global__ __launch_bounds__(256) void prep_kernel(
    const float* __restrict__ W, unsigned short* __restrict__ Wb,
    const int* __restrict__ dst, int* __restrict__ cnt, int n_edges)
{
    const int tid = blockIdx.x * 256 + threadIdx.x;
    if (tid < (D * D) / 8) {
        float4 v0 = *(const float4*)&W[tid * 8];
        float4 v1 = *(const float4*)&W[tid * 8 + 4];
        *(short8*)&Wb[tid * 8] = pack_bf16x8(v0, v1);
    }
    const int stride = gridDim.x * 256;
    for (int i = tid; i < n_edges; i += stride)
        atomicAdd(&cnt[dst[i]], 1);
}

// ---- GEMM: h(bf16) = relu(x @ W^T + b) * (mask_u >= 0.5) * 2 ---------------
// One 64-node tile per block. A: f32 from global + cvt (each row read once).
// B: short8 straight from L1/L2-resident Wb. LDS only for epilogue transpose.
__global__ __launch_bounds__(256, 4) void gemm_mfma_kernel(
    const float* __restrict__ x, const unsigned short* __restrict__ Wb,
    const float* __restrict__ bias, const float* __restrict__ mask_u,
    unsigned short* __restrict__ h, int n_nodes)
{
    __shared__ unsigned short ht[TILE_N * HPITCH];   // 16896 B
    const int t    = threadIdx.x;
    const int lane = t & 63;
    const int w    = t >> 6;      // wave -> 16-row strip of the tile
    const int fr   = lane & 15;
    const int fg   = lane >> 4;

    const int n0 = blockIdx.x * TILE_N;

    float bs[8];
    #pragma unroll
    for (int c = 0; c < 8; ++c) bs[c] = bias[16 * c + fr];

    int arow = n0 + 16 * w + fr;
    if (arow >= n_nodes) arow = n_nodes - 1;          // clamped (safe dup loads)
    const float* xrow = x + (size_t)arow * D;

    f32x4 acc[8];
    #pragma unroll
    for (int c = 0; c < 8; ++c) acc[c] = (f32x4){0.f, 0.f, 0.f, 0.f};

    #pragma unroll
    for (int s = 0; s < 4; ++s) {                     // K = 128, 4 x 32
        float4 a0 = *(const float4*)&xrow[s * 32 + fg * 8];
        float4 a1 = *(const float4*)&xrow[s * 32 + fg * 8 + 4];
        short8 a  = pack_bf16x8(a0, a1);
        #pragma unroll
        for (int c = 0; c < 8; ++c) {
            short8 b = *(const short8*)&Wb[(16 * c + fr) * D + s * 32 + fg * 8];
            acc[c] = __builtin_amdgcn_mfma_f32_16x16x32_bf16(a, b, acc[c], 0, 0, 0);
        }
    }

    // phase 1: bias + relu, scatter bf16 into LDS tile (conflict-free, pitch 132)
    #pragma unroll
    for (int c = 0; c < 8; ++c) {
        const int col = 16 * c + fr;
        #pragma unroll
        for (int r = 0; r < 4; ++r) {
            const int rl = 16 * w + fg * 4 + r;
            float v = fmaxf(acc[c][r] + bs[c], 0.f);
            ht[rl * HPITCH + col] = f32_to_bf16(v);
        }
    }
    __syncthreads();

    // phase 2: dropout + fully coalesced mask loads / h stores
    const int cg = t & 15;                            // 8-col group
    const int r0 = t >> 4;                            // 0..15
    #pragma unroll
    for (int rr = 0; rr < 4; ++rr) {
        const int row  = 16 * rr + r0;
        const int node = n0 + row;
        if (node < n_nodes) {
            short8 hv = *(const short8*)&ht[row * HPITCH + cg * 8];
            const size_t off = (size_t)node * D + cg * 8;
            float4 m0 = *(const float4*)&mask_u[off];
            float4 m1 = *(const float4*)&mask_u[off + 4];
            short8 o;
            #pragma unroll
            for (int j = 0; j < 8; ++j) {
                float mk = (j < 4) ? ((const float*)&m0)[j] : ((const float*)&m1)[j - 4];
                float v  = bf16_to_f32((unsigned short)hv[j]) * 2.f;
                o[j] = (mk >= 0.5f) ? (short)f32_to_bf16(v) : (short)0;
            }
            *(short8*)&h[off] = o;
        }
    }
}

// ---------------- CSR build: scan + bucket scatter --------------------------
__global__ __launch_bounds__(256) void scan_partial_kernel(
    const int* __restrict__ cnt, int* __restrict__ bsum, int n)
{
    __shared__ int s[256];
    int t = threadIdx.x;
    int i = blockIdx.x * 256 + t;
    s[t] = (i < n) ? cnt[i] : 0;
    __syncthreads();
    for (int o = 128; o > 0; o >>= 1) {
        if (t < o) s[t] += s[t + o];
        __syncthreads();
    }
    if (t == 0) bsum[blockIdx.x] = s[0];
}

__global__ __launch_bounds__(256) void scan_bsum_kernel(int* __restrict__ bsum, int nb)
{
    __shared__ int s[256];
    int t = threadIdx.x;
    int v = (t < nb) ? bsum[t] : 0;
    s[t] = v;
    __syncthreads();
    for (int o = 1; o < 256; o <<= 1) {
        int add = (t >= o) ? s[t - o] : 0;
        __syncthreads();
        s[t] += add;
        __syncthreads();
    }
    if (t < nb) bsum[t] = s[t] - v;   // exclusive
}

__global__ __launch_bounds__(256) void scan_final_kernel(
    int* __restrict__ offs, const int* __restrict__ bsum, int n)
{
    __shared__ int s[256];
    int t = threadIdx.x;
    int i = blockIdx.x * 256 + t;
    int v = (i < n) ? offs[i] : 0;
    s[t] = v;
    __syncthreads();
    for (int o = 1; o < 256; o <<= 1) {
        int add = (t >= o) ? s[t - o] : 0;
        __syncthreads();
        s[t] += add;
        __syncthreads();
    }
    if (i < n) offs[i] = s[t] - v + bsum[blockIdx.x];
}

__global__ __launch_bounds__(256) void scatter_build_kernel(
    const int* __restrict__ src, const int* __restrict__ dst,
    int* __restrict__ offs, int* __restrict__ srcs, int n_edges)
{
    int i = blockIdx.x * 256 + threadIdx.x;
    if (i < n_edges) {
        int pos = atomicAdd(&offs[dst[i]], 1);
        srcs[pos] = src[i];
    }
}

// ---- Gather-reduce (bf16 h): out[n] = sum_{e: dst=n} h[src_e] --------------
// 16 lanes/node, short8 per lane; 4-edge unroll for load-latency ILP.
__global__ __launch_bounds__(256) void gather_reduce_kernel(
    const unsigned short* __restrict__ h, const int* __restrict__ srcs,
    const int* __restrict__ offs, float* __restrict__ out, int n_nodes)
{
    const int t = threadIdx.x;
    const int node = blockIdx.x * 16 + (t >> 4);
    if (node >= n_nodes) return;
    const int cb = (t & 15) * 8;
    const int start = (node == 0) ? 0 : offs[node - 1];
    const int end   = offs[node];
    float acc[8];
    #pragma unroll
    for (int j = 0; j < 8; ++j) acc[j] = 0.f;

    int i = start;
    for (; i + 3 < end; i += 4) {
        int s0 = srcs[i],     s1 = srcs[i + 1];
        int s2 = srcs[i + 2], s3 = srcs[i + 3];
        short8 v0 = *(const short8*)&h[(size_t)s0 * D + cb];
        short8 v1 = *(const short8*)&h[(size_t)s1 * D + cb];
        short8 v2 = *(const short8*)&h[(size_t)s2 * D + cb];
        short8 v3 = *(const short8*)&h[(size_t)s3 * D + cb];
        #pragma unroll
        for (int j = 0; j < 8; ++j)
            acc[j] += (bf16_to_f32((unsigned short)v0[j]) +
                       bf16_to_f32((unsigned short)v1[j])) +
                      (bf16_to_f32((unsigned short)v2[j]) +
                       bf16_to_f32((unsigned short)v3[j]));
    }
    for (; i < end; ++i) {
        int s0 = srcs[i];
        short8 v0 = *(const short8*)&h[(size_t)s0 * D + cb];
        #pragma unroll
        for (int j = 0; j < 8; ++j) acc[j] += bf16_to_f32((unsigned short)v0[j]);
    }

    // streamed output, never re-read: non-temporal (clang ext-vector type)
    f32x4 o0 = (f32x4){acc[0], acc[1], acc[2], acc[3]};
    f32x4 o1 = (f32x4){acc[4], acc[5], acc[6], acc[7]};
    __builtin_nontemporal_store(o0, (f32x4*)&out[(size_t)node * D + cb]);
    __builtin_nontemporal_store(o1, (f32x4*)&out[(size_t)node * D + cb + 4]);
}

// ---------------- Fallback: direct atomic scatter (bf16 h) ------------------
__global__ __launch_bounds__(256) void scatter_atomic_kernel(
    const unsigned short* __restrict__ h, const int* __restrict__ src,
    const int* __restrict__ dst, float* __restrict__ out, int n_edges)
{
    const int t = threadIdx.x;
    const int e = blockIdx.x * 16 + (t >> 4);
    if (e >= n_edges) return;
    const int cb = (t & 15) * 8;
    const int s  = src[e];
    const int dd = dst[e];
    short8 v = *(const short8*)&h[(size_t)s * D + cb];
    float* o = &out[(size_t)dd * D + cb];
    #pragma unroll
    for (int j = 0; j < 8; ++j) atomicAdd(o + j, bf16_to_f32((unsigned short)v[j]));
}

extern "C" void kernel_launch(void* const* d_in, const int* in_sizes, int n_in,
                              void* d_out, int out_size, void* d_ws, size_t ws_size,
                              hipStream_t stream) {
    const float* x      = (const float*)d_in[0];
    const float* W      = (const float*)d_in[1];
    const float* bias   = (const float*)d_in[2];
    const float* mask_u = (const float*)d_in[3];
    const int*   src    = (const int*)d_in[4];
    const int*   dst    = (const int*)d_in[5];
    float* out = (float*)d_out;

    const int n_nodes = in_sizes[0] / D;
    const int n_edges = in_sizes[4];
    const int n_tiles = (n_nodes + TILE_N - 1) / TILE_N;

    // ws layout: [Wb bf16 64KB][h bf16][offs][bsum 256][srcs]
    unsigned short* Wb = (unsigned short*)d_ws;
    const size_t wb_bytes = (size_t)D * D * sizeof(unsigned short);
    unsigned short* h  = (unsigned short*)((char*)d_ws + wb_bytes);
    const size_t h_bytes = (size_t)n_nodes * D * sizeof(unsigned short);
    int* offs = (int*)((char*)d_ws + wb_bytes + h_bytes);
    int* bsum = offs + n_nodes;
    int* srcs = bsum + 256;
    const size_t needed = wb_bytes + h_bytes +
                          ((size_t)n_nodes + 256 + n_edges) * sizeof(int);

    const int eb  = (n_edges + 255) / 256;
    const int nbk = (n_nodes + 255) / 256;
    const int pb  = (eb > 8) ? eb : 8;     // prep grid covers W conv + hist

    if (ws_size >= needed && nbk <= 256) {
        zero_kernel<<<nbk, 256, 0, stream>>>(offs, n_nodes);
        prep_kernel<<<pb, 256, 0, stream>>>(W, Wb, dst, offs, n_edges);
        gemm_mfma_kernel<<<n_tiles, 256, 0, stream>>>(
            x, Wb, bias, mask_u, h, n_nodes);
        scan_partial_kernel<<<nbk, 256, 0, stream>>>(offs, bsum, n_nodes);
        scan_bsum_kernel<<<1, 256, 0, stream>>>(bsum, nbk);
        scan_final_kernel<<<nbk, 256, 0, stream>>>(offs, bsum, n_nodes);
        scatter_build_kernel<<<eb, 256, 0, stream>>>(src, dst, offs, srcs, n_edges);
        gather_reduce_kernel<<<(n_nodes + 15) / 16, 256, 0, stream>>>(
            h, srcs, offs, out, n_nodes);
    } else {
        prep_kernel<<<8, 256, 0, stream>>>(W, Wb, dst, nullptr, 0);
        gemm_mfma_kernel<<<n_tiles, 256, 0, stream>>>(
            x, Wb, bias, mask_u, h, n_nodes);
        zero_kernel<<<(out_size + 255) / 256, 256, 0, stream>>>((int*)d_out, out_size);
        scatter_atomic_kernel<<<(n_edges + 15) / 16, 256, 0, stream>>>(
            h, src, dst, out, n_edges);
    }
}